// Round 7
// baseline (1289.150 us; speedup 1.0000x reference)
//
#include <hip/hip_runtime.h>
#include <cstdint>
#include <cstddef>

typedef unsigned short u16;
typedef unsigned char u8;
typedef unsigned int u32;

typedef short s16x8 __attribute__((ext_vector_type(8)));
typedef float f32x4 __attribute__((ext_vector_type(4)));

// ---------------- helpers ----------------
__device__ __forceinline__ float b2f(u16 h){ u32 u = ((u32)h)<<16; float f; __builtin_memcpy(&f,&u,4); return f; }
__device__ __forceinline__ u16 f2b(float x){ u32 u; __builtin_memcpy(&u,&x,4); u += 0x7fffu + ((u>>16)&1u); return (u16)(u>>16); }
// fast gate math: v_rcp instead of full-precision divide (~1e-6 rel err, way under bf16 noise)
__device__ __forceinline__ float sigf(float x){ return __builtin_amdgcn_rcpf(1.f+__expf(-x)); }
__device__ __forceinline__ float tanh2(float x){
  float ax=fabsf(x); float e=__expf(-2.f*ax);
  float r=(1.f-e)*__builtin_amdgcn_rcpf(1.f+e);
  return x<0.f? -r : r;
}

typedef __attribute__((address_space(1))) const void gvoid_t;
typedef __attribute__((address_space(3))) void lvoid_t;
__device__ __forceinline__ void gl_lds16(const u16* src, u16* dst){
  __builtin_amdgcn_global_load_lds((gvoid_t*)src, (lvoid_t*)dst, 16, 0, 0);
}

// saddr-form coherent ops: uniform SGPR base + 32-bit lane voffset (0 VALU addressing)
__device__ __forceinline__ s16x8 gload16_coh_s(const u16* sbase, u32 voff){
  s16x8 r;
  asm volatile("global_load_dwordx4 %0, %1, %2 sc0 sc1" : "=v"(r) : "v"(voff), "s"(sbase) : "memory");
  return r;
}
__device__ __forceinline__ float gloadf_s(const float* sbase, u32 voff){
  float r;
  asm volatile("global_load_dword %0, %1, %2" : "=v"(r) : "v"(voff), "s"(sbase) : "memory");
  return r;
}
__device__ __forceinline__ void st_u16_coh_s(u16* sbase, u32 voff, u16 v){
  asm volatile("global_store_short %0, %1, %2 sc0 sc1" :: "v"(voff), "v"((u32)v), "s"(sbase) : "memory");
}
__device__ __forceinline__ void st_f32_coh_s(float* sbase, u32 voff, float v){
  asm volatile("global_store_dword %0, %1, %2 sc0 sc1" :: "v"(voff), "v"(v), "s"(sbase) : "memory");
}
// pinned full-pointer 16B load (used once for weights)
__device__ __forceinline__ s16x8 gload16(const u16* p){
  s16x8 r;
  asm volatile("global_load_dwordx4 %0, %1, off" : "=v"(r) : "v"(p) : "memory");
  return r;
}

// ---------------- mask dtype detection + packed mask codes ----------------
__global__ void detect_mask_mode(const u8* raw, int n, int* flag){
  __shared__ int cnt;
  int tid = threadIdx.x;
  if(tid==0) cnt=0;
  __syncthreads();
  int c=0;
  for(int i=tid;i<n;i+=blockDim.x) c += (raw[i]!=0);
  atomicAdd(&cnt, c);
  __syncthreads();
  if(tid==0) *flag = (cnt > (n>>2)) ? 1 : 0;  // 1 => byte-per-element layout
}

// code[i] = done | main<<1 | mainNext<<2
__global__ void build_mcode(const void* done_raw, const void* main_raw, u8* code, int n, const int* flag){
  int mode = *flag;
  for(int i = blockIdx.x*blockDim.x + threadIdx.x; i<n; i += gridDim.x*blockDim.x){
    u8 d, m, m2;
    if(mode){
      d = ((const u8*)done_raw)[i]!=0; m = ((const u8*)main_raw)[i]!=0;
      m2 = (i+256<n) ? (((const u8*)main_raw)[i+256]!=0) : (u8)0;
    } else {
      d = ((const int*)done_raw)[i]!=0; m = ((const int*)main_raw)[i]!=0;
      m2 = (i+256<n) ? (((const int*)main_raw)[i+256]!=0) : (u8)0;
    }
    code[i] = d | (m<<1) | (m2<<2);
  }
}

__global__ void zero_flags(int* p, int n){
  int i = threadIdx.x;
  if(i<n) p[i]=0;
}

// ---------------- conversions ----------------
__global__ void cvt_f32_bf16(const float* __restrict__ in, u16* __restrict__ out, int n4){
  int i = blockIdx.x*blockDim.x + threadIdx.x;
  if(i < n4){
    float4 v = ((const float4*)in)[i];
    ushort4 o;
    o.x=f2b(v.x); o.y=f2b(v.y); o.z=f2b(v.z); o.w=f2b(v.w);
    ((ushort4*)out)[i]=o;
  }
}

// in [R][C] f32  ->  out [C][R] bf16
__global__ void transpose_to_bf16(const float* __restrict__ in, u16* __restrict__ out, int R, int C){
  __shared__ float tile[64][65];
  int c0 = blockIdx.x*64, r0 = blockIdx.y*64;
  int tx = threadIdx.x & 63, ty = threadIdx.x >> 6;   // 256 threads
  for(int i=ty;i<64;i+=4) tile[i][tx] = in[(size_t)(r0+i)*C + c0 + tx];
  __syncthreads();
  for(int i=ty;i<64;i+=4) out[(size_t)(c0+i)*R + r0 + tx] = f2b(tile[tx][i]);
}

__global__ void init_hsel(const float* __restrict__ h1in, const float* __restrict__ h2in,
                          const u8* __restrict__ mcode, u16* __restrict__ hsel0){
  int i = blockIdx.x*blockDim.x + threadIdx.x;
  if(i < 256*1024){
    int row = i >> 10;
    hsel0[i] = f2b((mcode[row]&2) ? h1in[i] : h2in[i]);
  }
}

// ---------------- phase 1: Zx = x @ Wi + b  (m97-style 128x128 tile) ----------------
template<bool ZF32>
__global__ __launch_bounds__(256) void gemm_zx(const u16* __restrict__ A, const u16* __restrict__ Bt,
                                               const float* __restrict__ bias, void* __restrict__ Cout,
                                               int M, int N, int K){
  __shared__ u16 As[128*32];
  __shared__ u16 Bs[128*32];
  int nbx = N>>7, nby = M>>7;
  int nwg = nbx*nby;                 // 8192, divisible by 8
  int gid = blockIdx.x;
  int per = nwg>>3;
  int g2 = (gid&7)*per + (gid>>3);   // XCD-contiguous remap (bijective: nwg%8==0)
  int tpg = 8*nbx;                   // 8-row supergroup x all cols
  int grp = g2/tpg, w = g2%tpg;
  int brow = grp*8 + (w & 7);
  int bcol = w >> 3;
  int row0 = brow<<7, col0 = bcol<<7;

  int tid=threadIdx.x, wid=tid>>6, lane=tid&63;
  int l15=lane&15, hi=lane>>4;
  int wm=(wid>>1)<<6, wn=(wid&1)<<6;

  f32x4 acc[4][4];
  #pragma unroll
  for(int m=0;m<4;m++)
    #pragma unroll
    for(int n=0;n<4;n++) acc[m][n]=(f32x4){0.f,0.f,0.f,0.f};

  for(int k0=0;k0<K;k0+=32){
    __syncthreads();
    #pragma unroll
    for(int q=0;q<2;q++){
      int cb=q*256+wid*64;
      int ch=cb+lane;
      gl_lds16(A + (size_t)(row0+(ch>>2))*K + k0 + (ch&3)*8, &As[cb*8]);
    }
    #pragma unroll
    for(int q=0;q<2;q++){
      int cb=q*256+wid*64;
      int ch=cb+lane;
      gl_lds16(Bt + (size_t)(col0+(ch>>2))*K + k0 + (ch&3)*8, &Bs[cb*8]);
    }
    __syncthreads();
    s16x8 a[4], b[4];
    #pragma unroll
    for(int m=0;m<4;m++) a[m] = *(const s16x8*)&As[(wm+m*16+l15)*32 + hi*8];
    #pragma unroll
    for(int n=0;n<4;n++) b[n] = *(const s16x8*)&Bs[(wn+n*16+l15)*32 + hi*8];
    #pragma unroll
    for(int m=0;m<4;m++)
      #pragma unroll
      for(int n=0;n<4;n++)
        acc[m][n] = __builtin_amdgcn_mfma_f32_16x16x32_bf16(a[m],b[n],acc[m][n],0,0,0);
  }
  #pragma unroll
  for(int m=0;m<4;m++){
    #pragma unroll
    for(int n=0;n<4;n++){
      #pragma unroll
      for(int j=0;j<4;j++){
        int r = row0+wm+m*16+hi*4+j;
        int c = col0+wn+n*16+l15;
        float v = acc[m][n][j] + bias[c];
        if(ZF32) ((float*)Cout)[(size_t)r*N+c]=v;
        else     ((u16*)Cout)[(size_t)r*N+c]=f2b(v);
      }
    }
  }
}

// ---------------- phase 2: persistent recurrent kernel (K-split waves) ----------------
// Structure as R6 (proven): 256 blocks x 512 thr, rg=bid&7 (32 rows), jg=bid>>3
// (32 hcols); wave: gate=wid>>1, kg=wid&1 (K-half); breg 128 VGPR/wave.
// R7 changes: (1) all per-step addressing strength-reduced to t-invariant lane
// voffsets + SGPR bases advanced by constants (saddr-form asm); (2) ds_read/
// ds_write via 2 base pointers + compile-time immediates; (3) rcp-based gates;
// (4) packed mask codes (2 loads/step); (5) barrier-free release via LDS wave
// counter (top-of-step barrier still covers the zpart/As anti-race).
template<bool ZF32>
__global__ __launch_bounds__(512) __attribute__((amdgpu_waves_per_eu(2,2)))
void lstm_persist(
    const void* __restrict__ Zx, const u16* __restrict__ Wht,
    u16* __restrict__ hs0, u16* __restrict__ hs1,
    const float* __restrict__ c1i, const float* __restrict__ h1i,
    const float* __restrict__ c2i, const float* __restrict__ h2i,
    const u8* __restrict__ mcode,
    float* __restrict__ out, int* __restrict__ ready)
{
  __shared__ u16 As[32768];            // 64 KB h tile, XOR-swizzled
  __shared__ float zpart[4*2*32*33];   // 33 KB K-half partials
  __shared__ int lcnt[2];              // per-parity wave-completion counters

  const int bid = blockIdx.x;
  const int rg = bid & 7, jg = bid >> 3;
  const int r0 = rg << 5, j0 = jg << 5;
  const int tid = threadIdx.x, wid = tid >> 6, lane = tid & 63;
  const int l15 = lane & 15, hi = lane >> 4;
  const int gate = wid >> 1, kg = wid & 1;
  const int srow = tid >> 4, sc16 = tid & 15;
  const int erow = tid >> 5, ecol = tid & 31;

  if(tid < 2) lcnt[tid] = 0;

  // ---- Wh^T fragments (once): 32 x s16x8 = 128 VGPRs ----
  s16x8 breg[2][16];
  {
    #pragma unroll
    for(int n=0;n<2;n++){
      const u16* wp = Wht + ((size_t)(gate*1024 + j0 + n*16 + l15))*1024 + kg*512 + hi*8;
      #pragma unroll
      for(int kk=0;kk<16;kk++) breg[n][kk] = gload16(wp + kk*32);
    }
    asm volatile("s_waitcnt vmcnt(0)" ::: "memory");
    __builtin_amdgcn_sched_barrier(0);
  }

  // ---- states into registers (once) ----
  float c1r[2],c2r[2],h1r[2],h2r[2];
  #pragma unroll
  for(int e=0;e<2;e++){
    size_t sidx = (size_t)(r0 + e*16 + erow)*1024 + j0 + ecol;
    c1r[e]=c1i[sidx]; c2r[e]=c2i[sidx]; h1r[e]=h1i[sidx]; h2r[e]=h2i[sidx];
  }

  // ---- t-invariant lane voffsets (bytes) ----
  u32 voffS[8];                                    // staging loads (and h layout)
  #pragma unroll
  for(int kc=0;kc<8;kc++) voffS[kc] = (u32)(((r0+srow)*1024 + (kc*16+sc16)*8)*2);
  u32 voffH[2], voffO[2];
  #pragma unroll
  for(int e=0;e<2;e++){
    u32 idx = (u32)((r0 + e*16 + erow)*1024 + j0 + ecol);
    voffH[e] = idx*2;                              // bf16 h
    voffO[e] = idx*4;                              // f32 out (per-step base advances)
  }
  u32 voffZ[8];                                    // [g*2+e], f32 Zx
  #pragma unroll
  for(int g=0;g<4;g++)
    #pragma unroll
    for(int e=0;e<2;e++)
      voffZ[g*2+e] = (u32)((((r0 + e*16 + erow)*4096) + g*1024 + j0 + ecol)*4);

  // LDS base pointers (t-invariant)
  u16* pS = &As[sc16*256 + ((srow ^ (sc16&7))<<3)];                    // staging writes
  const u16* pAe = &As[kg*16384 + hi*256 + ((l15 ^  hi   )<<3)];       // even-kk reads
  const u16* pAo = &As[kg*16384 + hi*256 + ((l15 ^ (4+hi))<<3)];       // odd-kk reads
  float* pzw = &zpart[((gate*2+kg)*32 + hi*4)*33 + l15];
  const float* pzr = &zpart[erow*33 + ecol];

  // uniform per-step bases
  const char* zstep = (const char*)Zx;
  const u16* Zb16 = (const u16*)Zx;
  float* outp = out;
  const u8* mp = mcode + r0;
  int* flag = ready + rg*32;

  #pragma unroll 1
  for(int t=0;t<128;t++){
    // ---- Zx + mask prefetch (issued before the spin; drained by staging vmcnt0) ----
    float zr[4][2];
    if(ZF32){
      #pragma unroll
      for(int g=0;g<4;g++)
        #pragma unroll
        for(int e=0;e<2;e++)
          zr[g][e] = gloadf_s((const float*)zstep, voffZ[g*2+e]);
    } else {
      #pragma unroll
      for(int g=0;g<4;g++)
        #pragma unroll
        for(int e=0;e<2;e++)
          zr[g][e] = b2f(Zb16[(size_t)(t*256 + r0 + e*16 + erow)*4096 + g*1024 + j0 + ecol]);
    }
    u8 cd0 = mp[erow], cd1 = mp[16+erow];

    // ---- chain wait ----
    if(t>0 && tid==0){
      while(__hip_atomic_load(flag, __ATOMIC_RELAXED, __HIP_MEMORY_SCOPE_AGENT) < 32*t)
        __builtin_amdgcn_s_sleep(1);
    }
    __syncthreads();                 // also fences prior-step zpart/As readers
    __builtin_amdgcn_sched_barrier(0);

    const u16* hinp = (t&1) ? hs1 : hs0;
    u16* houtp = (t&1) ? hs0 : hs1;

    // ---- stage h tile (coherent point-reads -> swizzled LDS) ----
    {
      s16x8 hv[8];
      #pragma unroll
      for(int kc=0;kc<8;kc++) hv[kc] = gload16_coh_s(hinp, voffS[kc]);
      asm volatile("s_waitcnt vmcnt(0)" ::: "memory");   // drains Zx too
      #pragma unroll
      for(int kc=0;kc<8;kc++) *(s16x8*)(pS + kc*4096) = hv[kc];
    }
    __syncthreads();

    // ---- recurrent GEMM: this wave's K-half, 64 MFMA, B in registers ----
    f32x4 acc[2][2];
    #pragma unroll
    for(int m=0;m<2;m++)
      #pragma unroll
      for(int n=0;n<2;n++) acc[m][n]=(f32x4){0.f,0.f,0.f,0.f};
    #pragma unroll
    for(int kk=0;kk<16;kk++){
      const u16* p = (kk&1) ? pAo : pAe;
      s16x8 a0 = *(const s16x8*)(p + kk*1024);
      s16x8 a1 = *(const s16x8*)(p + kk*1024 + 128);
      acc[0][0] = __builtin_amdgcn_mfma_f32_16x16x32_bf16(a0, breg[0][kk], acc[0][0], 0,0,0);
      acc[0][1] = __builtin_amdgcn_mfma_f32_16x16x32_bf16(a0, breg[1][kk], acc[0][1], 0,0,0);
      acc[1][0] = __builtin_amdgcn_mfma_f32_16x16x32_bf16(a1, breg[0][kk], acc[1][0], 0,0,0);
      acc[1][1] = __builtin_amdgcn_mfma_f32_16x16x32_bf16(a1, breg[1][kk], acc[1][1], 0,0,0);
    }

    // ---- K-half partial exchange ----
    #pragma unroll
    for(int m=0;m<2;m++)
      #pragma unroll
      for(int n=0;n<2;n++)
        #pragma unroll
        for(int j=0;j<4;j++)
          pzw[m*528 + j*33 + n*16] = acc[m][n][j];
    __syncthreads();

    // ---- epilogue ----
    float nhv[2];
    #pragma unroll
    for(int e=0;e<2;e++){
      u8 cd = e ? cd1 : cd0;
      float zi  = zr[0][e] + pzr[0*1056 + e*528] + pzr[1*1056 + e*528];
      float zf_ = zr[1][e] + pzr[2*1056 + e*528] + pzr[3*1056 + e*528];
      float zg  = zr[2][e] + pzr[4*1056 + e*528] + pzr[5*1056 + e*528];
      float zo  = zr[3][e] + pzr[6*1056 + e*528] + pzr[7*1056 + e*528];
      bool d_ = cd & 1, m_ = cd & 2, m2 = cd & 4;
      float co = m_ ? c1r[e] : c2r[e];
      float nc = sigf(zf_)*co + sigf(zi)*tanh2(zg);
      float nhx = sigf(zo)*tanh2(nc);
      nhv[e] = nhx;
      float n1c = m_?nc:c1r[e], n2c = m_?c2r[e]:nc;
      float n1h = m_?nhx:h1r[e], n2h = m_?h2r[e]:nhx;
      if(d_){ n1c=0.f; n2c=0.f; n1h=0.f; n2h=0.f; }
      c1r[e]=n1c; c2r[e]=n2c; h1r[e]=n1h; h2r[e]=n2h;
      if(t<127)
        st_u16_coh_s(houtp, voffH[e], f2b(m2 ? n1h : n2h));
    }

    // ---- per-wave drain + LDS-counted release (no block barrier) ----
    if(t<127){
      asm volatile("s_waitcnt vmcnt(0)" ::: "memory");   // this wave's h at CP
      if(lane==0){
        int c = atomicAdd(&lcnt[t&1], 1);
        if(c==7){
          lcnt[t&1] = 0;
          __hip_atomic_fetch_add(flag, 1, __ATOMIC_RELAXED, __HIP_MEMORY_SCOPE_AGENT);
        }
      }
    }

    // ---- out store off the critical path ----
    #pragma unroll
    for(int e=0;e<2;e++)
      st_f32_coh_s(outp, voffO[e], nhv[e]);

    zstep += 4194304;    // 256*4096*4 B
    outp  += 262144;     // 256*1024 floats
    mp    += 256;
  }
}

// ---------------- host ----------------
extern "C" void kernel_launch(void* const* d_in, const int* in_sizes, int n_in,
                              void* d_out, int out_size, void* d_ws, size_t ws_size,
                              hipStream_t stream){
  const float* x   = (const float*)d_in[0];
  const float* c1i = (const float*)d_in[1];
  const float* h1i = (const float*)d_in[2];
  const float* c2i = (const float*)d_in[3];
  const float* h2i = (const float*)d_in[4];
  const float* Wi  = (const float*)d_in[5];
  const float* Wh  = (const float*)d_in[6];
  const float* bias= (const float*)d_in[7];
  const void* done_raw = d_in[8];
  const void* main_raw = d_in[9];
  float* out = (float*)d_out;

  char* ws = (char*)d_ws;
  size_t off=0;
  auto alloc=[&](size_t sz)->char*{ char* p = ws+off; off += (sz+255)&~(size_t)255; return p; };

  u16* xb   = (u16*)alloc(33554432ull*2);        // x as bf16 [32768][1024]
  u16* WiT  = (u16*)alloc(4096ull*1024*2);       // Wi^T bf16 [4096][1024]
  u16* WhT  = (u16*)alloc(4096ull*1024*2);       // Wh^T bf16 [4096][1024]
  u16* hs0  = (u16*)alloc(262144ull*2);
  u16* hs1  = (u16*)alloc(262144ull*2);
  u8* mcode = (u8*)alloc(32768);
  int* flag = (int*)alloc(256);
  int* ready= (int*)alloc(1024);

  bool zf32 = (off + 536870912ull) <= ws_size;   // Zx fp32 if workspace allows
  void* Zx  = (void*)alloc(zf32 ? 536870912ull : 268435456ull);

  detect_mask_mode<<<1,256,0,stream>>>((const u8*)done_raw, 32768, flag);
  build_mcode<<<64,256,0,stream>>>(done_raw, main_raw, mcode, 32768, flag);
  cvt_f32_bf16<<<32768,256,0,stream>>>(x, xb, 8388608);
  transpose_to_bf16<<<dim3(64,16),256,0,stream>>>(Wi, WiT, 1024, 4096);
  transpose_to_bf16<<<dim3(64,16),256,0,stream>>>(Wh, WhT, 1024, 4096);
  init_hsel<<<1024,256,0,stream>>>(h1i, h2i, mcode, hs0);
  zero_flags<<<1,256,0,stream>>>(ready, 256);

  if(zf32) gemm_zx<true ><<<8192,256,0,stream>>>(xb, WiT, bias, Zx, 32768, 4096, 1024);
  else     gemm_zx<false><<<8192,256,0,stream>>>(xb, WiT, bias, Zx, 32768, 4096, 1024);

  if(zf32)
    lstm_persist<true ><<<256,512,0,stream>>>(Zx,WhT,hs0,hs1,c1i,h1i,c2i,h2i,mcode,out,ready);
  else
    lstm_persist<false><<<256,512,0,stream>>>(Zx,WhT,hs0,hs1,c1i,h1i,c2i,h2i,mcode,out,ready);
}